// Round 9
// baseline (1052.770 us; speedup 1.0000x reference)
//
#include <hip/hip_runtime.h>
#include <hip/hip_cooperative_groups.h>

namespace cg = cooperative_groups;

// ---------------------------------------------------------------------------
// HybridSAGEClassifier: 3x SAGEConv(mean) + BN + ReLU, then fusion MLP.
// R1: project-first. R2: ELL + register gather. R6: MFMA bf16x3 split.
// R12: direct global A-loads. R13/R14/R16/R17/R19/R21 FAILED (see history).
// R15: gather floor ~71us (per-CU miss cap x latency; 7 rounds stable).
// R18: prep_all fusion; 17->9 nodes. 480us.
// R22 WIN: XCD-local fill (shard = bid&7 -> atomics L2-local). 470us.
// R23 WIN: fill+gemm1 merged (co-scheduled). 463.7us.
// R24 (this): accounting shows ~174us in 4 small kernels + 8 boundaries
//      that bottom-up models say should be ~30us+overhead. Hypotheses:
//      (a) dependent-dispatch boundary cost (ramp + tail + cross-XCD L2
//      writeback/invalidate), (b) kernels genuinely slow. Decisive
//      experiment that also fixes (a): cooperative persistent MEGA-kernel
//      -- all 8 stages in ONE dispatch, grid.sync() between stages.
//      Grid sized via occupancy API; LDS union 21.5KB; fill keeps bid&7
//      XCD affinity; fusion reads Wf1 direct (no sW1) to fit the union.
//      Fallback to the R23 multi-kernel path if cooperative launch fails.
// ---------------------------------------------------------------------------

typedef __attribute__((ext_vector_type(8))) short bf16x8;
typedef __attribute__((ext_vector_type(4))) float f32x4;

#define ELLS 48
#define SMB 21504  // LDS union: gemm 21248 (sW 20480 + sSS 512 + sB 256)

struct MegaArgs {
  const int* ei;
  const float* x;
  const float* xgb;
  const float *W1l, *b1, *W1r, *g1, *be1;
  const float *W2l, *b2, *W2r, *g2, *be2;
  const float *W3l, *b3, *W3r, *g3, *be3;
  const float *Wf1, *bf1, *Wf2, *bf2;
  float* out;
  int* deg;
  int* ell;
  ushort *Ybf, *Yrbf, *Tbf;
  ushort *Whi1, *Wlo1, *Whi2, *Wlo2, *Whi3, *Wlo3;
  float* stats;
  int n, E, nblk, F;
};

__device__ __forceinline__ ushort f2bf(float f) {
  unsigned u = __float_as_uint(f);
  return (ushort)((u + 0x7fff + ((u >> 16) & 1)) >> 16);  // RNE
}
__device__ __forceinline__ float bf2f(ushort h) {
  return __uint_as_float((unsigned)h << 16);
}
__device__ __forceinline__ void unpack8(uint4 v, float* f) {
  f[0] = __uint_as_float(v.x << 16);
  f[1] = __uint_as_float(v.x & 0xffff0000u);
  f[2] = __uint_as_float(v.y << 16);
  f[3] = __uint_as_float(v.y & 0xffff0000u);
  f[4] = __uint_as_float(v.z << 16);
  f[5] = __uint_as_float(v.z & 0xffff0000u);
  f[6] = __uint_as_float(v.w << 16);
  f[7] = __uint_as_float(v.w & 0xffff0000u);
}

// ---- stage 0: prep (deg/stats/sentinel zero + 3x W bf16-split) -------------

__device__ __forceinline__ void prep_one(const float* __restrict__ Wl,
                                         const float* __restrict__ Wr,
                                         ushort* __restrict__ Whi,
                                         ushort* __restrict__ Wlo, int din,
                                         int i) {
  int col = i / din, k = i % din;
  float v = (col < 64) ? Wl[(size_t)k * 64 + col]
                       : Wr[(size_t)k * 64 + (col - 64)];
  ushort h = f2bf(v);
  Whi[i] = h;
  Wlo[i] = f2bf(v - bf2f(h));
}

__device__ __forceinline__ void prep_block(const MegaArgs& a, int vb, int nbd,
                                           int tid) {
  if (vb < nbd) {
    int i = vb * 256 + tid;
    if (i < a.n + 4) a.deg[i] = 0;
    return;
  }
  vb -= nbd;
  if (vb < 64) { prep_one(a.W1l, a.W1r, a.Whi1, a.Wlo1, 128, vb * 256 + tid); return; }
  vb -= 64;
  if (vb < 32) { prep_one(a.W2l, a.W2r, a.Whi2, a.Wlo2, 64, vb * 256 + tid); return; }
  vb -= 32;
  if (vb < 32) { prep_one(a.W3l, a.W3r, a.Whi3, a.Wlo3, 64, vb * 256 + tid); return; }
  if (tid < 384) a.stats[tid] = 0.f;
  if (tid < 64) a.Ybf[(size_t)a.n * 64 + tid] = 0;  // zero sentinel row
}

// ---- fill role: XCD-local sharded scatter (R22-exact) ----------------------

__device__ __forceinline__ void fill_role(const MegaArgs& a, int bid, int bps) {
  const int tid = threadIdx.x;
  const int shard = bid & 7;  // XCD-affine (round-robin dispatch)
  const int bib = bid >> 3;
  const int chunk = a.n >> 3;
  const int lo = shard * chunk;
  const int hi = (shard == 7) ? a.n : lo + chunk;
  const int stride = bps * 256 * 4;
  const int E4 = a.E & ~3;
  for (int e = (bib * 256 + tid) * 4; e < E4; e += stride) {
    int4 d4 = *reinterpret_cast<const int4*>(a.ei + a.E + e);
    int4 s4 = *reinterpret_cast<const int4*>(a.ei + e);
    if (d4.x >= lo && d4.x < hi) {
      int p = atomicAdd(&a.deg[d4.x], 1);
      if (p < ELLS) a.ell[(size_t)d4.x * ELLS + p] = s4.x;
    }
    if (d4.y >= lo && d4.y < hi) {
      int p = atomicAdd(&a.deg[d4.y], 1);
      if (p < ELLS) a.ell[(size_t)d4.y * ELLS + p] = s4.y;
    }
    if (d4.z >= lo && d4.z < hi) {
      int p = atomicAdd(&a.deg[d4.z], 1);
      if (p < ELLS) a.ell[(size_t)d4.z * ELLS + p] = s4.z;
    }
    if (d4.w >= lo && d4.w < hi) {
      int p = atomicAdd(&a.deg[d4.w], 1);
      if (p < ELLS) a.ell[(size_t)d4.w * ELLS + p] = s4.w;
    }
  }
  if (bid == 0) {  // scalar tail for E%4
    for (int e = E4 + tid; e < a.E; e += 256) {
      int d = a.ei[a.E + e];
      int s = a.ei[e];
      int pos = atomicAdd(&a.deg[d], 1);
      if (pos < ELLS) a.ell[(size_t)d * ELLS + pos] = s;
    }
  }
}

// ---- gemm tile (R18-exact body; smem via union pointer) --------------------

template <int DIN, bool NORM, bool XBF16>
__device__ __forceinline__ void gemm_tile(char* smraw, int tile,
    const void* __restrict__ Xv, const float* __restrict__ stats,
    const float* __restrict__ g, const float* __restrict__ be,
    const float* __restrict__ bias, const ushort* __restrict__ Whi,
    const ushort* __restrict__ Wlo, ushort* __restrict__ Ybf,
    ushort* __restrict__ Yrbf, int n) {
  constexpr int WS = 40;
  ushort* sW = (ushort*)smraw;                 // 2*128*40 ushorts = 20480B
  float* sSS = (float*)(smraw + 20480);        // 128 floats
  float* sB = (float*)(smraw + 20992);         // 64 floats
  const int tid = threadIdx.x;
  const int w = tid >> 6;
  const int lane = tid & 63;
  const int m = lane & 15;
  const int quad = lane >> 4;
  const int row0 = tile * 64;

  if (tid < 64) {
    sB[tid] = bias[tid];
    if (NORM) {
      float invn = 1.0f / (float)n;
      float mu = stats[tid] * invn;
      float var = fmaf(-mu, mu, stats[64 + tid] * invn);
      float sc = g[tid] * rsqrtf(var + 1e-5f);
      sSS[tid] = sc;
      sSS[64 + tid] = fmaf(-mu, sc, be[tid]);
    }
  }

  const int arow = min(row0 + w * 16 + m, n - 1);

  f32x4 acc[8];
#pragma unroll
  for (int t = 0; t < 8; t++) acc[t] = (f32x4){0.f, 0.f, 0.f, 0.f};

  for (int kc = 0; kc < DIN; kc += 32) {
    __syncthreads();  // prev sW reads done / sSS+sB ready
    for (int i = tid; i < 512; i += 256) {
      int col = i >> 2;
      int k = (i & 3) * 8;
      *reinterpret_cast<uint4*>(sW + col * WS + k) =
          *reinterpret_cast<const uint4*>(Whi + (size_t)col * DIN + kc + k);
      *reinterpret_cast<uint4*>(sW + 128 * WS + col * WS + k) =
          *reinterpret_cast<const uint4*>(Wlo + (size_t)col * DIN + kc + k);
    }
    __syncthreads();

    const int kb = kc + quad * 8;
    float av[8];
    if (XBF16) {
      const ushort* X = (const ushort*)Xv;
      uint4 v = *reinterpret_cast<const uint4*>(X + (size_t)arow * DIN + kb);
      unpack8(v, av);
    } else {
      const float* X = (const float*)Xv;
      const float* ap = X + (size_t)arow * DIN + kb;
      float4 a0 = *reinterpret_cast<const float4*>(ap);
      float4 a1 = *reinterpret_cast<const float4*>(ap + 4);
      av[0] = a0.x; av[1] = a0.y; av[2] = a0.z; av[3] = a0.w;
      av[4] = a1.x; av[5] = a1.y; av[6] = a1.z; av[7] = a1.w;
    }
    if (NORM) {
#pragma unroll
      for (int j = 0; j < 8; j++)
        av[j] = fmaxf(fmaf(av[j], sSS[kb + j], sSS[64 + kb + j]), 0.f);
    }
    bf16x8 Ahi, Alo;
#pragma unroll
    for (int j = 0; j < 8; j++) {
      ushort h = f2bf(av[j]);
      Ahi[j] = (short)h;
      Alo[j] = (short)f2bf(av[j] - bf2f(h));
    }
#pragma unroll
    for (int t = 0; t < 8; t++) {
      bf16x8 Bhi =
          *reinterpret_cast<const bf16x8*>(sW + (t * 16 + m) * WS + quad * 8);
      bf16x8 Blo = *reinterpret_cast<const bf16x8*>(sW + 128 * WS +
                                                    (t * 16 + m) * WS + quad * 8);
      acc[t] = __builtin_amdgcn_mfma_f32_16x16x32_bf16(Ahi, Bhi, acc[t], 0, 0, 0);
      acc[t] = __builtin_amdgcn_mfma_f32_16x16x32_bf16(Ahi, Blo, acc[t], 0, 0, 0);
      acc[t] = __builtin_amdgcn_mfma_f32_16x16x32_bf16(Alo, Bhi, acc[t], 0, 0, 0);
    }
  }

#pragma unroll
  for (int t = 0; t < 8; t++) {
    int col = t * 16 + m;
#pragma unroll
    for (int r = 0; r < 4; r++) {
      int grow = row0 + w * 16 + quad * 4 + r;
      if (grow < n) {
        float v = acc[t][r];
        if (t < 4) {
          Ybf[(size_t)grow * 64 + col] = f2bf(v);
        } else {
          Yrbf[(size_t)grow * 64 + (col - 64)] = f2bf(v + sB[col - 64]);
        }
      }
    }
  }
}

// ---- gather stage (R15 structure + deg-clamp; grid-stride) -----------------

__device__ void gather_stage(char* smraw, const MegaArgs& a,
                             float* __restrict__ statsL, int bid, int nblk) {
  float* rS = (float*)smraw;          // [4][64]
  float* rQ = (float*)(smraw + 1024); // [4][64]
  const int lane = threadIdx.x & 63;
  const int w = threadIdx.x >> 6;
  const int grp = lane >> 3;
  const int sub = lane & 7;
  const int wid = bid * 4 + w;
  const int nw = nblk * 4;
  const int n = a.n;
  const ushort* __restrict__ Ybf = a.Ybf;
  const ushort* __restrict__ Yrbf = a.Yrbf;
  const int* __restrict__ ell = a.ell;
  float ssum[8], ssq[8];
#pragma unroll
  for (int c = 0; c < 8; c++) ssum[c] = ssq[c] = 0.f;

  for (int base = wid * 4; base < n; base += nw * 4) {
    int4 dg4 = *reinterpret_cast<const int4*>(a.deg + base);  // padded +4
    int dg[4] = {dg4.x, dg4.y, dg4.z, dg4.w};
    int mx = 0;
#pragma unroll
    for (int j = 0; j < 4; j++) mx = max(mx, min(dg[j], ELLS));
    float acc[4][8];
#pragma unroll
    for (int j = 0; j < 4; j++)
#pragma unroll
      for (int c = 0; c < 8; c++) acc[j][c] = 0.f;

    for (int e0 = 0; e0 < mx; e0 += 8) {
      int idx = e0 + grp;
      int s0 = ell[(size_t)(base + 0) * ELLS + idx];
      int s1 = ell[(size_t)(base + 1) * ELLS + idx];
      int s2 = ell[(size_t)(base + 2) * ELLS + idx];
      int s3 = ell[(size_t)(base + 3) * ELLS + idx];
      s0 = (idx < dg[0]) ? s0 : n;  // clamp garbage slots to sentinel
      s1 = (idx < dg[1]) ? s1 : n;
      s2 = (idx < dg[2]) ? s2 : n;
      s3 = (idx < dg[3]) ? s3 : n;
      uint4 v0 = *reinterpret_cast<const uint4*>(Ybf + (size_t)s0 * 64 + sub * 8);
      uint4 v1 = *reinterpret_cast<const uint4*>(Ybf + (size_t)s1 * 64 + sub * 8);
      uint4 v2 = *reinterpret_cast<const uint4*>(Ybf + (size_t)s2 * 64 + sub * 8);
      uint4 v3 = *reinterpret_cast<const uint4*>(Ybf + (size_t)s3 * 64 + sub * 8);
      float f[8];
      unpack8(v0, f);
#pragma unroll
      for (int c = 0; c < 8; c++) acc[0][c] += f[c];
      unpack8(v1, f);
#pragma unroll
      for (int c = 0; c < 8; c++) acc[1][c] += f[c];
      unpack8(v2, f);
#pragma unroll
      for (int c = 0; c < 8; c++) acc[2][c] += f[c];
      unpack8(v3, f);
#pragma unroll
      for (int c = 0; c < 8; c++) acc[3][c] += f[c];
    }
#pragma unroll
    for (int mmask = 8; mmask <= 32; mmask <<= 1)
#pragma unroll
      for (int j = 0; j < 4; j++)
#pragma unroll
        for (int c = 0; c < 8; c++)
          acc[j][c] += __shfl_xor(acc[j][c], mmask, 64);

    if (lane < 8) {
#pragma unroll
      for (int j = 0; j < 4; j++) {
        int node = base + j;
        if (node >= n) continue;
        float iv = 1.0f / (float)max(dg[j], 1);
        uint4 yrv =
            *reinterpret_cast<const uint4*>(Yrbf + (size_t)node * 64 + sub * 8);
        float yr[8];
        unpack8(yrv, yr);
        float t[8];
#pragma unroll
        for (int c = 0; c < 8; c++) {
          t[c] = fmaf(acc[j][c], iv, yr[c]);  // bias already in Yrbf
          ssum[c] += t[c];
          ssq[c] = fmaf(t[c], t[c], ssq[c]);
        }
        uint4 o;
        o.x = (uint)f2bf(t[0]) | ((uint)f2bf(t[1]) << 16);
        o.y = (uint)f2bf(t[2]) | ((uint)f2bf(t[3]) << 16);
        o.z = (uint)f2bf(t[4]) | ((uint)f2bf(t[5]) << 16);
        o.w = (uint)f2bf(t[6]) | ((uint)f2bf(t[7]) << 16);
        *reinterpret_cast<uint4*>(a.Tbf + (size_t)node * 64 + sub * 8) = o;
      }
    }
  }
  __syncthreads();  // smem may hold prior stage data; claim it
  if (lane < 8) {
#pragma unroll
    for (int c = 0; c < 8; c++) {
      rS[w * 64 + sub * 8 + c] = ssum[c];
      rQ[w * 64 + sub * 8 + c] = ssq[c];
    }
  }
  __syncthreads();
  if (threadIdx.x < 64) {
    int tc = threadIdx.x;
    float s = rS[tc] + rS[64 + tc] + rS[128 + tc] + rS[192 + tc];
    float qq = rQ[tc] + rQ[64 + tc] + rQ[128 + tc] + rQ[192 + tc];
    atomicAdd(&statsL[tc], s);
    atomicAdd(&statsL[64 + tc], qq);
  }
}

// ---- fusion tile (BN3+ReLU fused; Wf1/Wf2 direct from L1) ------------------

__device__ __forceinline__ void fusion_tile(char* smraw, int tile,
                                            const MegaArgs& a) {
  float* sH = (float*)smraw;            // 64*64 floats = 16384B
  float* fS = (float*)(smraw + 16384);  // 128 floats
  const int tid = threadIdx.x;
  const int c = tid & 63;
  const int w = tid >> 6;
  const int row0 = tile * 64;
  const int n = a.n;
  const float* stats3 = a.stats + 256;
  __syncthreads();  // claim smem from prior stage
  if (tid < 64) {
    float invn = 1.0f / (float)n;
    float mu = stats3[tid] * invn;
    float var = fmaf(-mu, mu, stats3[64 + tid] * invn);
    float sc = a.g3[tid] * rsqrtf(var + 1e-5f);
    fS[tid] = sc;
    fS[64 + tid] = fmaf(-mu, sc, a.be3[tid]);
  }
  __syncthreads();
  for (int i = tid; i < 512; i += 256) {
    int r = i >> 3;
    int k = (i & 7) * 8;
    int row = min(row0 + r, n - 1);
    uint4 v = *reinterpret_cast<const uint4*>(a.Tbf + (size_t)row * 64 + k);
    float f[8];
    unpack8(v, f);
#pragma unroll
    for (int j = 0; j < 8; j++)
      f[j] = fmaxf(fmaf(f[j], fS[k + j], fS[64 + k + j]), 0.f);
    *reinterpret_cast<float4*>(sH + r * 64 + k) =
        make_float4(f[0], f[1], f[2], f[3]);
    *reinterpret_cast<float4*>(sH + r * 64 + k + 4) =
        make_float4(f[4], f[5], f[6], f[7]);
  }
  __syncthreads();
  const float b1v = a.bf1[c];
  const float wx = a.Wf1[64 * 64 + c];
  const float w2v = a.Wf2[c];
  const float b2v = a.bf2[0];
  float acc[16];
#pragma unroll
  for (int r = 0; r < 16; r++) acc[r] = b1v;
  for (int kk = 0; kk < 64; kk += 4) {
    float4 hv[16];
#pragma unroll
    for (int r = 0; r < 16; r++)
      hv[r] = *reinterpret_cast<const float4*>(sH + (w * 16 + r) * 64 + kk);
    float w0 = a.Wf1[(kk + 0) * 64 + c];
    float w1 = a.Wf1[(kk + 1) * 64 + c];
    float w2 = a.Wf1[(kk + 2) * 64 + c];
    float w3 = a.Wf1[(kk + 3) * 64 + c];
#pragma unroll
    for (int r = 0; r < 16; r++) {
      acc[r] = fmaf(hv[r].x, w0, acc[r]);
      acc[r] = fmaf(hv[r].y, w1, acc[r]);
      acc[r] = fmaf(hv[r].z, w2, acc[r]);
      acc[r] = fmaf(hv[r].w, w3, acc[r]);
    }
  }
#pragma unroll
  for (int r = 0; r < 16; r++) {
    int row = row0 + w * 16 + r;
    float xv = (row < n) ? a.xgb[row] : 0.f;
    float z = fmaxf(fmaf(xv, wx, acc[r]), 0.f) * w2v;
#pragma unroll
    for (int off = 32; off > 0; off >>= 1) z += __shfl_xor(z, off, 64);
    if (row < n && c == 0) a.out[row] = z + b2v;
  }
}

// ---- the cooperative mega-kernel -------------------------------------------

__global__ __launch_bounds__(256) void mega(MegaArgs a) {
  __shared__ __align__(16) char sm[SMB];
  cg::grid_group gg = cg::this_grid();
  const int bid = blockIdx.x;
  const int tid = threadIdx.x;
  const int G = (a.n + 63) / 64;
  const int nbd = (a.n + 4 + 255) / 256;
  const int nvb = nbd + 64 + 32 + 32 + 1;

  for (int vb = bid; vb < nvb; vb += a.nblk) prep_block(a, vb, nbd, tid);
  gg.sync();

  if (bid < a.F) {
    fill_role(a, bid, a.F >> 3);
  } else {
    for (int t = bid - a.F; t < G; t += a.nblk - a.F)
      gemm_tile<128, false, false>(sm, t, a.x, nullptr, nullptr, nullptr, a.b1,
                                   a.Whi1, a.Wlo1, a.Ybf, a.Yrbf, a.n);
  }
  gg.sync();

  gather_stage(sm, a, a.stats, bid, a.nblk);
  gg.sync();

  for (int t = bid; t < G; t += a.nblk)
    gemm_tile<64, true, true>(sm, t, a.Tbf, a.stats, a.g1, a.be1, a.b2, a.Whi2,
                              a.Wlo2, a.Ybf, a.Yrbf, a.n);
  gg.sync();

  gather_stage(sm, a, a.stats + 128, bid, a.nblk);
  gg.sync();

  for (int t = bid; t < G; t += a.nblk)
    gemm_tile<64, true, true>(sm, t, a.Tbf, a.stats + 128, a.g2, a.be2, a.b3,
                              a.Whi3, a.Wlo3, a.Ybf, a.Yrbf, a.n);
  gg.sync();

  gather_stage(sm, a, a.stats + 256, bid, a.nblk);
  gg.sync();

  for (int t = bid; t < G; t += a.nblk) fusion_tile(sm, t, a);
}

// ---- fallback wrappers (R23 multi-kernel path) -----------------------------

__global__ __launch_bounds__(256) void prep_k(MegaArgs a) {
  prep_block(a, blockIdx.x, (a.n + 4 + 255) / 256, threadIdx.x);
}
__global__ __launch_bounds__(256) void fillgemm1_k(MegaArgs a) {
  __shared__ __align__(16) char sm[SMB];
  const int G = (a.n + 63) / 64;
  if ((int)blockIdx.x < a.F) {
    fill_role(a, blockIdx.x, a.F >> 3);
    return;
  }
  int t = blockIdx.x - a.F;
  if (t < G)
    gemm_tile<128, false, false>(sm, t, a.x, nullptr, nullptr, nullptr, a.b1,
                                 a.Whi1, a.Wlo1, a.Ybf, a.Yrbf, a.n);
}
__global__ __launch_bounds__(256) void gemm_k(MegaArgs a, int layer) {
  __shared__ __align__(16) char sm[SMB];
  if (layer == 2)
    gemm_tile<64, true, true>(sm, blockIdx.x, a.Tbf, a.stats, a.g1, a.be1,
                              a.b2, a.Whi2, a.Wlo2, a.Ybf, a.Yrbf, a.n);
  else
    gemm_tile<64, true, true>(sm, blockIdx.x, a.Tbf, a.stats + 128, a.g2,
                              a.be2, a.b3, a.Whi3, a.Wlo3, a.Ybf, a.Yrbf, a.n);
}
__global__ __launch_bounds__(256) void gather_k(MegaArgs a, int so) {
  __shared__ __align__(16) char sm2[2048];
  gather_stage(sm2, a, a.stats + so, blockIdx.x, gridDim.x);
}
__global__ __launch_bounds__(256) void fusion_k(MegaArgs a) {
  __shared__ __align__(16) char sm[SMB];
  fusion_tile(sm, blockIdx.x, a);
}

// ---- launch ----------------------------------------------------------------

extern "C" void kernel_launch(void* const* d_in, const int* in_sizes, int n_in,
                              void* d_out, int out_size, void* d_ws,
                              size_t ws_size, hipStream_t stream) {
  const float* x = (const float*)d_in[0];
  const int* ei = (const int*)d_in[1];
  const float* xgb = (const float*)d_in[2];

  const int n = in_sizes[2];      // 100000
  const int E = in_sizes[1] / 2;  // 1200000

  char* w = (char*)d_ws;
  auto alloc = [&](size_t bytes) {
    void* p = (void*)w;
    w += (bytes + 255) & ~(size_t)255;
    return p;
  };
  int* deg = (int*)alloc((size_t)(n + 4) * 4);
  int* ell = (int*)alloc((size_t)(n + 4) * ELLS * 4);
  ushort* Ybf = (ushort*)alloc((size_t)(n + 1) * 64 * 2);  // +1 sentinel row
  ushort* Yrbf = (ushort*)alloc((size_t)n * 64 * 2);
  ushort* Tbf = (ushort*)alloc((size_t)n * 64 * 2);
  ushort* Whi1 = (ushort*)alloc(128 * 128 * 2);
  ushort* Wlo1 = (ushort*)alloc(128 * 128 * 2);
  ushort* Whi2 = (ushort*)alloc(128 * 64 * 2);
  ushort* Wlo2 = (ushort*)alloc(128 * 64 * 2);
  ushort* Whi3 = (ushort*)alloc(128 * 64 * 2);
  ushort* Wlo3 = (ushort*)alloc(128 * 64 * 2);
  float* stats = (float*)alloc(3 * 128 * 4);

  MegaArgs ma;
  ma.ei = ei; ma.x = x; ma.xgb = xgb;
  ma.W1l = (const float*)d_in[3];  ma.b1 = (const float*)d_in[4];
  ma.W1r = (const float*)d_in[5];  ma.g1 = (const float*)d_in[6];
  ma.be1 = (const float*)d_in[7];
  ma.W2l = (const float*)d_in[8];  ma.b2 = (const float*)d_in[9];
  ma.W2r = (const float*)d_in[10]; ma.g2 = (const float*)d_in[11];
  ma.be2 = (const float*)d_in[12];
  ma.W3l = (const float*)d_in[13]; ma.b3 = (const float*)d_in[14];
  ma.W3r = (const float*)d_in[15]; ma.g3 = (const float*)d_in[16];
  ma.be3 = (const float*)d_in[17];
  ma.Wf1 = (const float*)d_in[18]; ma.bf1 = (const float*)d_in[19];
  ma.Wf2 = (const float*)d_in[20]; ma.bf2 = (const float*)d_in[21];
  ma.out = (float*)d_out;
  ma.deg = deg; ma.ell = ell;
  ma.Ybf = Ybf; ma.Yrbf = Yrbf; ma.Tbf = Tbf;
  ma.Whi1 = Whi1; ma.Wlo1 = Wlo1; ma.Whi2 = Whi2; ma.Wlo2 = Wlo2;
  ma.Whi3 = Whi3; ma.Wlo3 = Wlo3;
  ma.stats = stats;
  ma.n = n; ma.E = E;

  // grid size = co-resident capacity (occupancy API), multiple of 8
  static int s_nblk = 0;
  if (s_nblk == 0) {
    int perCU = 0;
    if (hipOccupancyMaxActiveBlocksPerMultiprocessor(
            &perCU, reinterpret_cast<const void*>(mega), 256, 0) !=
            hipSuccess ||
        perCU <= 0)
      perCU = 4;
    int ncu = 256;
    hipDeviceProp_t prop;
    int dev = 0;
    (void)hipGetDevice(&dev);
    if (hipGetDeviceProperties(&prop, dev) == hipSuccess &&
        prop.multiProcessorCount > 0)
      ncu = prop.multiProcessorCount;
    s_nblk = (perCU * ncu) & ~7;
    if (s_nblk < 256) s_nblk = 256;
  }
  ma.nblk = s_nblk;
  ma.F = ((s_nblk * 2) / 5) & ~7;  // fill-block share (XCD-affine, mult of 8)
  if (ma.F < 8) ma.F = 8;

  void* kargs[] = {(void*)&ma};
  hipError_t err = hipLaunchCooperativeKernel(
      reinterpret_cast<const void*>(mega), dim3(s_nblk), dim3(256), kargs, 0,
      stream);
  if (err != hipSuccess) {
    (void)hipGetLastError();  // clear; replay proven R23 path
    MegaArgs mb = ma;
    mb.F = 1024;
    const int G = (n + 63) / 64;
    const int nbd = (n + 4 + 255) / 256;
    prep_k<<<nbd + 129, 256, 0, stream>>>(mb);
    fillgemm1_k<<<mb.F + G, 256, 0, stream>>>(mb);
    gather_k<<<2048, 256, 0, stream>>>(mb, 0);
    gemm_k<<<G, 256, 0, stream>>>(mb, 2);
    gather_k<<<2048, 256, 0, stream>>>(mb, 128);
    gemm_k<<<G, 256, 0, stream>>>(mb, 3);
    gather_k<<<2048, 256, 0, stream>>>(mb, 256);
    fusion_k<<<G, 256, 0, stream>>>(mb);
  }
}

// Round 10
// 395.450 us; speedup vs baseline: 2.6622x; 2.6622x over previous
//
#include <hip/hip_runtime.h>

// ---------------------------------------------------------------------------
// HybridSAGEClassifier: 3x SAGEConv(mean) + BN + ReLU, then fusion MLP.
// R1: project-first (mean(x[src])@Wl == mean((x@Wl)[src])).
// R2: scatter-atomics -> CSR + register gather.
// R5: one-pass ELL; bf16 gather table.
// R6: MFMA 16x16x32_bf16, bf16x3 split (~fp32 accuracy).
// R12: direct global A-loads; ELL stride 48.
// R13/R14/R16/R17/R19/R21 FAILED (fetch-granularity / forced-bound /
//      MSHR-cap / nt-hints / LDS-epilogue / burst-atomics; see git log).
// R15: 60-VGPR gather (8 waves/SIMD), bias folded into GEMM epilogue.
// R18: prep_all fusion + deg-clamp gather; 17->9 nodes. 480us.
// R22 WIN: XCD-local fill (shard = bid&7). Fill 100+ -> <40us. 470us.
// R23 WIN: fill+gemm1 merged (co-scheduled). 463.7us = BEST.
// R24 FAILED: cooperative mega-kernel 970us -- union footprint collapsed
//      occupancy; grid.sync drains. Mono-kernel strictly worse. Reverted.
// R25 (this): stats atomic tail theory. All 2048 gather blocks finish
//      their evenly-strided loops simultaneously, then burst 2048
//      serialized atomicAdds PER stats address (262K RMWs, 128 addrs)
//      -> ~20-30us un-hidden tail inside each gather = part of the "71us
//      floor" no gather-loop variant touched. Fix: 8 stats copies indexed
//      by bid&7 (contention /8, XCD-aligned); consumers sum 8 copies in
//      their finalize (8 extra L2 loads for 64 threads, once). Everything
//      else R23-exact.
// ---------------------------------------------------------------------------

typedef __attribute__((ext_vector_type(8))) short bf16x8;
typedef __attribute__((ext_vector_type(4))) float f32x4;

#define ELLS 48  // ELL row stride

__device__ __forceinline__ ushort f2bf(float f) {
  unsigned u = __float_as_uint(f);
  return (ushort)((u + 0x7fff + ((u >> 16) & 1)) >> 16);  // RNE
}
__device__ __forceinline__ float bf2f(ushort h) {
  return __uint_as_float((unsigned)h << 16);
}
__device__ __forceinline__ void unpack8(uint4 v, float* f) {
  f[0] = __uint_as_float(v.x << 16);
  f[1] = __uint_as_float(v.x & 0xffff0000u);
  f[2] = __uint_as_float(v.y << 16);
  f[3] = __uint_as_float(v.y & 0xffff0000u);
  f[4] = __uint_as_float(v.z << 16);
  f[5] = __uint_as_float(v.z & 0xffff0000u);
  f[6] = __uint_as_float(v.w << 16);
  f[7] = __uint_as_float(v.w & 0xffff0000u);
}

// ---- combined prep: deg/stats/sentinel zero + 3x W bf16-split --------------

__device__ __forceinline__ void prep_one(const float* __restrict__ Wl,
                                         const float* __restrict__ Wr,
                                         ushort* __restrict__ Whi,
                                         ushort* __restrict__ Wlo, int din,
                                         int i) {
  int col = i / din, k = i % din;
  float v = (col < 64) ? Wl[(size_t)k * 64 + col]
                       : Wr[(size_t)k * 64 + (col - 64)];
  ushort h = f2bf(v);
  Whi[i] = h;
  Wlo[i] = f2bf(v - bf2f(h));
}

__global__ __launch_bounds__(256) void prep_all(
    const float* __restrict__ W1l, const float* __restrict__ W1r,
    ushort* __restrict__ Whi1, ushort* __restrict__ Wlo1,
    const float* __restrict__ W2l, const float* __restrict__ W2r,
    ushort* __restrict__ Whi2, ushort* __restrict__ Wlo2,
    const float* __restrict__ W3l, const float* __restrict__ W3r,
    ushort* __restrict__ Whi3, ushort* __restrict__ Wlo3,
    int* __restrict__ deg, float* __restrict__ stats,
    ushort* __restrict__ sent, int n, int nbd) {
  int bid = blockIdx.x;
  const int tid = threadIdx.x;
  if (bid < nbd) {  // zero deg (n+4, int4-padded)
    int i = bid * 256 + tid;
    if (i < n + 4) deg[i] = 0;
    return;
  }
  bid -= nbd;
  if (bid < 64) {  // W1: 128x128
    prep_one(W1l, W1r, Whi1, Wlo1, 128, bid * 256 + tid);
    return;
  }
  bid -= 64;
  if (bid < 32) {  // W2: 128x64
    prep_one(W2l, W2r, Whi2, Wlo2, 64, bid * 256 + tid);
    return;
  }
  bid -= 32;
  if (bid < 32) {  // W3: 128x64
    prep_one(W3l, W3r, Whi3, Wlo3, 64, bid * 256 + tid);
    return;
  }
  // tail block: stats (3 layers x 8 copies x 128 = 3072 floats) + sentinel
  for (int i = tid; i < 3072; i += 256) stats[i] = 0.f;
  if (tid < 64) sent[tid] = 0;
}

// ---- merged XCD-local ELL-fill + layer-1 GEMM (R23-exact) ------------------
// Blocks [0,F): fill role, shard = bid & 7 (XCD-affine; R22-validated).
// Blocks [F,F+G): gemm1 tiles (DIN=128, fp32 X; bias folded into Yrbf).

__global__ __launch_bounds__(256) void fill_gemm1(
    const int* __restrict__ ei, int* __restrict__ deg, int* __restrict__ ell,
    int E, int n, int bps, const float* __restrict__ X,
    const float* __restrict__ bias, const ushort* __restrict__ Whi,
    const ushort* __restrict__ Wlo, ushort* __restrict__ Ybf,
    ushort* __restrict__ Yrbf, int F, int G) {
  constexpr int WS = 40;
  __shared__ ushort sW[2 * 128 * WS];
  __shared__ float sB[64];
  const int tid = threadIdx.x;
  const int bid = blockIdx.x;

  if (bid < F) {
    // ---------------- fill role (R22-exact) ----------------
    const int shard = bid & 7;   // XCD-affine
    const int bib = bid >> 3;    // 0..bps-1
    const int chunk = n >> 3;
    const int lo = shard * chunk;
    const int hi = (shard == 7) ? n : lo + chunk;
    const int stride = bps * 256 * 4;
    const int E4 = E & ~3;
    for (int e = (bib * 256 + tid) * 4; e < E4; e += stride) {
      int4 d4 = *reinterpret_cast<const int4*>(ei + E + e);
      int4 s4 = *reinterpret_cast<const int4*>(ei + e);
      if (d4.x >= lo && d4.x < hi) {
        int p = atomicAdd(&deg[d4.x], 1);
        if (p < ELLS) ell[(size_t)d4.x * ELLS + p] = s4.x;
      }
      if (d4.y >= lo && d4.y < hi) {
        int p = atomicAdd(&deg[d4.y], 1);
        if (p < ELLS) ell[(size_t)d4.y * ELLS + p] = s4.y;
      }
      if (d4.z >= lo && d4.z < hi) {
        int p = atomicAdd(&deg[d4.z], 1);
        if (p < ELLS) ell[(size_t)d4.z * ELLS + p] = s4.z;
      }
      if (d4.w >= lo && d4.w < hi) {
        int p = atomicAdd(&deg[d4.w], 1);
        if (p < ELLS) ell[(size_t)d4.w * ELLS + p] = s4.w;
      }
    }
    // tail (E not multiple of 4): shard 0's first block handles it scalar
    if (shard == 0 && bib == 0) {
      for (int e = E4 + tid; e < E; e += 256) {
        int d = ei[E + e];
        int s = ei[e];
        int pos = atomicAdd(&deg[d], 1);
        if (pos < ELLS) ell[(size_t)d * ELLS + pos] = s;
      }
    }
    return;
  }

  // ---------------- gemm1 role ----------------
  const int tile = bid - F;  // 0..G-1
  const int w = tid >> 6;
  const int lane = tid & 63;
  const int m = lane & 15;
  const int quad = lane >> 4;
  const int row0 = tile * 64;

  if (tid < 64) sB[tid] = bias[tid];

  const int arow = min(row0 + w * 16 + m, n - 1);

  f32x4 acc[8];
#pragma unroll
  for (int t = 0; t < 8; t++) acc[t] = (f32x4){0.f, 0.f, 0.f, 0.f};

  for (int kc = 0; kc < 128; kc += 32) {
    __syncthreads();
    for (int i = tid; i < 512; i += 256) {
      int col = i >> 2;
      int k = (i & 3) * 8;
      *reinterpret_cast<uint4*>(sW + col * WS + k) =
          *reinterpret_cast<const uint4*>(Whi + (size_t)col * 128 + kc + k);
      *reinterpret_cast<uint4*>(sW + 128 * WS + col * WS + k) =
          *reinterpret_cast<const uint4*>(Wlo + (size_t)col * 128 + kc + k);
    }
    __syncthreads();

    const int kb = kc + quad * 8;
    float av[8];
    const float* ap = X + (size_t)arow * 128 + kb;
    float4 a0 = *reinterpret_cast<const float4*>(ap);
    float4 a1 = *reinterpret_cast<const float4*>(ap + 4);
    av[0] = a0.x; av[1] = a0.y; av[2] = a0.z; av[3] = a0.w;
    av[4] = a1.x; av[5] = a1.y; av[6] = a1.z; av[7] = a1.w;
    bf16x8 Ahi, Alo;
#pragma unroll
    for (int j = 0; j < 8; j++) {
      ushort h = f2bf(av[j]);
      Ahi[j] = (short)h;
      Alo[j] = (short)f2bf(av[j] - bf2f(h));
    }
#pragma unroll
    for (int t = 0; t < 8; t++) {
      bf16x8 Bhi =
          *reinterpret_cast<const bf16x8*>(sW + (t * 16 + m) * WS + quad * 8);
      bf16x8 Blo = *reinterpret_cast<const bf16x8*>(sW + 128 * WS +
                                                    (t * 16 + m) * WS +
                                                    quad * 8);
      acc[t] = __builtin_amdgcn_mfma_f32_16x16x32_bf16(Ahi, Bhi, acc[t], 0, 0, 0);
      acc[t] = __builtin_amdgcn_mfma_f32_16x16x32_bf16(Ahi, Blo, acc[t], 0, 0, 0);
      acc[t] = __builtin_amdgcn_mfma_f32_16x16x32_bf16(Alo, Bhi, acc[t], 0, 0, 0);
    }
  }

#pragma unroll
  for (int t = 0; t < 8; t++) {
    int col = t * 16 + m;
#pragma unroll
    for (int r = 0; r < 4; r++) {
      int grow = row0 + w * 16 + quad * 4 + r;
      if (grow < n) {
        float v = acc[t][r];
        if (t < 4) {
          Ybf[(size_t)grow * 64 + col] = f2bf(v);
        } else {
          Yrbf[(size_t)grow * 64 + (col - 64)] = f2bf(v + sB[col - 64]);
        }
      }
    }
  }
}

// ---- MFMA dual GEMM (layers 2/3; 8-copy stats finalize) --------------------
// [Ybf | Yrbf+bias] = f(X) @ [Wl | Wr]; f = BN(stats,g,be)+ReLU.
// stats points to an 8x128 block of per-XCD partial sums.
template <int DIN, bool NORM, bool XBF16>
__global__ __launch_bounds__(256) void gemm_mfma(
    const void* __restrict__ Xv, const float* __restrict__ stats,
    const float* __restrict__ g, const float* __restrict__ be,
    const float* __restrict__ bias, const ushort* __restrict__ Whi,
    const ushort* __restrict__ Wlo, ushort* __restrict__ Ybf,
    ushort* __restrict__ Yrbf, int n) {
  constexpr int WS = 40;
  __shared__ ushort sW[2 * 128 * WS];
  __shared__ float sSS[128];
  __shared__ float sB[64];
  const int tid = threadIdx.x;
  const int w = tid >> 6;
  const int lane = tid & 63;
  const int m = lane & 15;
  const int quad = lane >> 4;
  const int row0 = blockIdx.x * 64;

  if (tid < 64) {
    sB[tid] = bias[tid];
    if (NORM) {
      float s0 = 0.f, q0 = 0.f;
#pragma unroll
      for (int k = 0; k < 8; k++) {
        s0 += stats[k * 128 + tid];
        q0 += stats[k * 128 + 64 + tid];
      }
      float invn = 1.0f / (float)n;
      float mu = s0 * invn;
      float var = fmaf(-mu, mu, q0 * invn);
      float sc = g[tid] * rsqrtf(var + 1e-5f);
      sSS[tid] = sc;
      sSS[64 + tid] = fmaf(-mu, sc, be[tid]);
    }
  }

  const int arow = min(row0 + w * 16 + m, n - 1);

  f32x4 acc[8];
#pragma unroll
  for (int t = 0; t < 8; t++) acc[t] = (f32x4){0.f, 0.f, 0.f, 0.f};

  for (int kc = 0; kc < DIN; kc += 32) {
    __syncthreads();  // prev sW reads done / sSS+sB ready (first iter)
    for (int i = tid; i < 512; i += 256) {
      int col = i >> 2;
      int k = (i & 3) * 8;
      *reinterpret_cast<uint4*>(sW + col * WS + k) =
          *reinterpret_cast<const uint4*>(Whi + (size_t)col * DIN + kc + k);
      *reinterpret_cast<uint4*>(sW + 128 * WS + col * WS + k) =
          *reinterpret_cast<const uint4*>(Wlo + (size_t)col * DIN + kc + k);
    }
    __syncthreads();

    const int kb = kc + quad * 8;
    float av[8];
    if (XBF16) {
      const ushort* X = (const ushort*)Xv;
      uint4 v = *reinterpret_cast<const uint4*>(X + (size_t)arow * DIN + kb);
      unpack8(v, av);
    } else {
      const float* X = (const float*)Xv;
      const float* ap = X + (size_t)arow * DIN + kb;
      float4 a0 = *reinterpret_cast<const float4*>(ap);
      float4 a1 = *reinterpret_cast<const float4*>(ap + 4);
      av[0] = a0.x; av[1] = a0.y; av[2] = a0.z; av[3] = a0.w;
      av[4] = a1.x; av[5] = a1.y; av[6] = a1.z; av[7] = a1.w;
    }
    if (NORM) {
#pragma unroll
      for (int j = 0; j < 8; j++)
        av[j] = fmaxf(fmaf(av[j], sSS[kb + j], sSS[64 + kb + j]), 0.f);
    }
    bf16x8 Ahi, Alo;
#pragma unroll
    for (int j = 0; j < 8; j++) {
      ushort h = f2bf(av[j]);
      Ahi[j] = (short)h;
      Alo[j] = (short)f2bf(av[j] - bf2f(h));
    }
#pragma unroll
    for (int t = 0; t < 8; t++) {
      bf16x8 Bhi =
          *reinterpret_cast<const bf16x8*>(sW + (t * 16 + m) * WS + quad * 8);
      bf16x8 Blo = *reinterpret_cast<const bf16x8*>(sW + 128 * WS +
                                                    (t * 16 + m) * WS +
                                                    quad * 8);
      acc[t] = __builtin_amdgcn_mfma_f32_16x16x32_bf16(Ahi, Bhi, acc[t], 0, 0, 0);
      acc[t] = __builtin_amdgcn_mfma_f32_16x16x32_bf16(Ahi, Blo, acc[t], 0, 0, 0);
      acc[t] = __builtin_amdgcn_mfma_f32_16x16x32_bf16(Alo, Bhi, acc[t], 0, 0, 0);
    }
  }

#pragma unroll
  for (int t = 0; t < 8; t++) {
    int col = t * 16 + m;
#pragma unroll
    for (int r = 0; r < 4; r++) {
      int grow = row0 + w * 16 + quad * 4 + r;
      if (grow < n) {
        float v = acc[t][r];
        if (t < 4) {
          Ybf[(size_t)grow * 64 + col] = f2bf(v);
        } else {
          Yrbf[(size_t)grow * 64 + (col - 64)] = f2bf(v + sB[col - 64]);
        }
      }
    }
  }
}

// ---- ELL gather (R15 structure; deg-clamp; 8-copy stats atomics) -----------
// grp=lane>>3 picks one of 8 edge slots; sub=lane&7 picks a col octet
// (uint4 = 8 bf16; 8 lanes cover the full 128B row = one fetch line).
// Slots >= deg contain garbage (no ell_init): clamp s -> n (zeroed sentinel
// row). Final stats atomics go to copy (blockIdx.x & 7): per-address
// contention 2048 -> 256 serialized RMWs (R25).
__global__ __launch_bounds__(256) void gather_combine(
    const ushort* __restrict__ Ybf, const ushort* __restrict__ Yrbf,
    const int* __restrict__ ell, const int* __restrict__ deg,
    ushort* __restrict__ Tbf, float* __restrict__ stats, int n) {
  const int lane = threadIdx.x & 63;
  const int w = threadIdx.x >> 6;
  const int grp = lane >> 3;
  const int sub = lane & 7;
  const int wid = blockIdx.x * 4 + w;
  const int nw = gridDim.x * 4;
  float ssum[8], ssq[8];
#pragma unroll
  for (int c = 0; c < 8; c++) ssum[c] = ssq[c] = 0.f;

  for (int base = wid * 4; base < n; base += nw * 4) {
    int4 dg4 = *reinterpret_cast<const int4*>(deg + base);  // deg padded +4
    int dg[4] = {dg4.x, dg4.y, dg4.z, dg4.w};
    int mx = 0;
#pragma unroll
    for (int j = 0; j < 4; j++) mx = max(mx, min(dg[j], ELLS));
    float a[4][8];
#pragma unroll
    for (int j = 0; j < 4; j++)
#pragma unroll
      for (int c = 0; c < 8; c++) a[j][c] = 0.f;

    for (int e0 = 0; e0 < mx; e0 += 8) {
      int idx = e0 + grp;
      int s0 = ell[(size_t)(base + 0) * ELLS + idx];
      int s1 = ell[(size_t)(base + 1) * ELLS + idx];
      int s2 = ell[(size_t)(base + 2) * ELLS + idx];
      int s3 = ell[(size_t)(base + 3) * ELLS + idx];
      s0 = (idx < dg[0]) ? s0 : n;  // clamp garbage slots to sentinel
      s1 = (idx < dg[1]) ? s1 : n;
      s2 = (idx < dg[2]) ? s2 : n;
      s3 = (idx < dg[3]) ? s3 : n;
      uint4 v0 = *reinterpret_cast<const uint4*>(Ybf + (size_t)s0 * 64 + sub * 8);
      uint4 v1 = *reinterpret_cast<const uint4*>(Ybf + (size_t)s1 * 64 + sub * 8);
      uint4 v2 = *reinterpret_cast<const uint4*>(Ybf + (size_t)s2 * 64 + sub * 8);
      uint4 v3 = *reinterpret_cast<const uint4*>(Ybf + (size_t)s3 * 64 + sub * 8);
      float f[8];
      unpack8(v0, f);
#pragma unroll
      for (int c = 0; c < 8; c++) a[0][c] += f[c];
      unpack8(v1, f);
#pragma unroll
      for (int c = 0; c < 8; c++) a[1][c] += f[c];
      unpack8(v2, f);
#pragma unroll
      for (int c = 0; c < 8; c++) a[2][c] += f[c];
      unpack8(v3, f);
#pragma unroll
      for (int c = 0; c < 8; c++) a[3][c] += f[c];
    }
#pragma unroll
    for (int mmask = 8; mmask <= 32; mmask <<= 1)
#pragma unroll
      for (int j = 0; j < 4; j++)
#pragma unroll
        for (int c = 0; c < 8; c++)
          a[j][c] += __shfl_xor(a[j][c], mmask, 64);

    if (lane < 8) {  // grp == 0: finalize; lane sub owns cols sub*8..+7
#pragma unroll
      for (int j = 0; j < 4; j++) {
        int node = base + j;
        if (node >= n) continue;
        float iv = 1.0f / (float)max(dg[j], 1);
        uint4 yrv =
            *reinterpret_cast<const uint4*>(Yrbf + (size_t)node * 64 + sub * 8);
        float yr[8];
        unpack8(yrv, yr);
        float t[8];
#pragma unroll
        for (int c = 0; c < 8; c++) {
          t[c] = fmaf(a[j][c], iv, yr[c]);  // bias already in Yrbf
          ssum[c] += t[c];
          ssq[c] = fmaf(t[c], t[c], ssq[c]);
        }
        uint4 o;
        o.x = (uint)f2bf(t[0]) | ((uint)f2bf(t[1]) << 16);
        o.y = (uint)f2bf(t[2]) | ((uint)f2bf(t[3]) << 16);
        o.z = (uint)f2bf(t[4]) | ((uint)f2bf(t[5]) << 16);
        o.w = (uint)f2bf(t[6]) | ((uint)f2bf(t[7]) << 16);
        *reinterpret_cast<uint4*>(Tbf + (size_t)node * 64 + sub * 8) = o;
      }
    }
  }
  __shared__ float rS[4][64];
  __shared__ float rQ[4][64];
  if (lane < 8) {
#pragma unroll
    for (int c = 0; c < 8; c++) {
      rS[w][sub * 8 + c] = ssum[c];
      rQ[w][sub * 8 + c] = ssq[c];
    }
  }
  __syncthreads();
  if (threadIdx.x < 64) {
    int tc = threadIdx.x;
    float s = rS[0][tc] + rS[1][tc] + rS[2][tc] + rS[3][tc];
    float qq = rQ[0][tc] + rQ[1][tc] + rQ[2][tc] + rQ[3][tc];
    float* sc = stats + (blockIdx.x & 7) * 128;  // per-XCD copy (R25)
    atomicAdd(&sc[tc], s);
    atomicAdd(&sc[64 + tc], qq);
  }
}

// ---- fusion MLP: layer-3 BN (8-copy stats) + ReLU fused, T in bf16 ---------

__global__ __launch_bounds__(256) void fusion_fused(
    const ushort* __restrict__ Tbf, const float* __restrict__ stats,
    const float* __restrict__ g, const float* __restrict__ be,
    const float* __restrict__ xgb, const float* __restrict__ Wf1,
    const float* __restrict__ bf1, const float* __restrict__ Wf2,
    const float* __restrict__ bf2, float* __restrict__ out, int n) {
  __shared__ float sH[64 * 64];
  __shared__ float sW1[65 * 64];
  __shared__ float sW2[64];
  __shared__ float sSS[128];
  const int tid = threadIdx.x;
  const int c = tid & 63;
  const int w = tid >> 6;
  const int row0 = blockIdx.x * 64;
  if (tid < 64) {
    float s0 = 0.f, q0 = 0.f;
#pragma unroll
    for (int k = 0; k < 8; k++) {
      s0 += stats[k * 128 + tid];
      q0 += stats[k * 128 + 64 + tid];
    }
    float invn = 1.0f / (float)n;
    float mu = s0 * invn;
    float var = fmaf(-mu, mu, q0 * invn);
    float sc = g[tid] * rsqrtf(var + 1e-5f);
    sSS[tid] = sc;
    sSS[64 + tid] = fmaf(-mu, sc, be[tid]);
  }
  for (int i = tid; i < 65 * 64; i += 256) sW1[i] = Wf1[i];
  if (tid < 64) sW2[tid] = Wf2[tid];
  __syncthreads();
  for (int i = tid; i < 512; i += 256) {
    int r = i >> 3;
    int k = (i & 7) * 8;
    int row = min(row0 + r, n - 1);
    uint4 v = *reinterpret_cast<const uint4*>(Tbf + (size_t)row * 64 + k);
    float f[8];
    unpack8(v, f);
#pragma unroll
    for (int j = 0; j < 8; j++)
      f[j] = fmaxf(fmaf(f[j], sSS[k + j], sSS[64 + k + j]), 0.f);
    *reinterpret_cast<float4*>(sH + r * 64 + k) =
        make_float4(f[0], f[1], f[2], f[3]);
    *reinterpret_cast<float4*>(sH + r * 64 + k + 4) =
        make_float4(f[4], f[5], f[6], f[7]);
  }
  __syncthreads();
  const float b1v = bf1[c];
  const float wx = sW1[64 * 64 + c];
  const float w2v = sW2[c];
  const float b2v = bf2[0];
  float acc[16];
#pragma unroll
  for (int r = 0; r < 16; r++) acc[r] = b1v;
  for (int kk = 0; kk < 64; kk += 4) {
    float4 hv[16];
#pragma unroll
    for (int r = 0; r < 16; r++)
      hv[r] = *reinterpret_cast<const float4*>(sH + (w * 16 + r) * 64 + kk);
    float w0 = sW1[(kk + 0) * 64 + c];
    float w1 = sW1[(kk + 1) * 64 + c];
    float w2 = sW1[(kk + 2) * 64 + c];
    float w3 = sW1[(kk + 3) * 64 + c];
#pragma unroll
    for (int r = 0; r < 16; r++) {
      acc[r] = fmaf(hv[r].x, w0, acc[r]);
      acc[r] = fmaf(hv[r].y, w1, acc[r]);
      acc[r] = fmaf(hv[r].z, w2, acc[r]);
      acc[r] = fmaf(hv[r].w, w3, acc[r]);
    }
  }
#pragma unroll
  for (int r = 0; r < 16; r++) {
    int row = row0 + w * 16 + r;
    float xv = (row < n) ? xgb[row] : 0.f;
    float z = fmaxf(fmaf(xv, wx, acc[r]), 0.f) * w2v;
#pragma unroll
    for (int off = 32; off > 0; off >>= 1) z += __shfl_xor(z, off, 64);
    if (row < n && c == 0) out[row] = z + b2v;
  }
}

// ---- launch ----------------------------------------------------------------

extern "C" void kernel_launch(void* const* d_in, const int* in_sizes, int n_in,
                              void* d_out, int out_size, void* d_ws,
                              size_t ws_size, hipStream_t stream) {
  const float* x = (const float*)d_in[0];
  const int* ei = (const int*)d_in[1];
  const float* xgb = (const float*)d_in[2];
  const float* W1l = (const float*)d_in[3];
  const float* b1 = (const float*)d_in[4];
  const float* W1r = (const float*)d_in[5];
  const float* g1 = (const float*)d_in[6];
  const float* be1 = (const float*)d_in[7];
  const float* W2l = (const float*)d_in[8];
  const float* b2 = (const float*)d_in[9];
  const float* W2r = (const float*)d_in[10];
  const float* g2 = (const float*)d_in[11];
  const float* be2 = (const float*)d_in[12];
  const float* W3l = (const float*)d_in[13];
  const float* b3 = (const float*)d_in[14];
  const float* W3r = (const float*)d_in[15];
  const float* g3 = (const float*)d_in[16];
  const float* be3 = (const float*)d_in[17];
  const float* Wf1 = (const float*)d_in[18];
  const float* bf1 = (const float*)d_in[19];
  const float* Wf2 = (const float*)d_in[20];
  const float* bf2 = (const float*)d_in[21];
  float* out = (float*)d_out;

  const int n = in_sizes[2];      // 100000
  const int E = in_sizes[1] / 2;  // 1200000

  char* w = (char*)d_ws;
  auto alloc = [&](size_t bytes) {
    void* p = (void*)w;
    w += (bytes + 255) & ~(size_t)255;
    return p;
  };
  int* deg = (int*)alloc((size_t)(n + 4) * 4);           // +4 pad for int4
  int* ell = (int*)alloc((size_t)(n + 4) * ELLS * 4);    // +4 pad rows
  ushort* Ybf = (ushort*)alloc((size_t)(n + 1) * 64 * 2);  // +1 zero row
  ushort* Yrbf = (ushort*)alloc((size_t)n * 64 * 2);
  ushort* Tbf = (ushort*)alloc((size_t)n * 64 * 2);
  ushort* Whi1 = (ushort*)alloc(128 * 128 * 2);
  ushort* Wlo1 = (ushort*)alloc(128 * 128 * 2);
  ushort* Whi2 = (ushort*)alloc(128 * 64 * 2);
  ushort* Wlo2 = (ushort*)alloc(128 * 64 * 2);
  ushort* Whi3 = (ushort*)alloc(128 * 64 * 2);
  ushort* Wlo3 = (ushort*)alloc(128 * 64 * 2);
  float* stats = (float*)alloc(3 * 8 * 128 * 4);  // 3 layers x 8 copies x 128

  // ---- single prep kernel: deg=0, stats=0, sentinel=0, 3x W bf16-split
  const int nbd = (n + 4 + 255) / 256;
  prep_all<<<nbd + 64 + 32 + 32 + 1, 256, 0, stream>>>(
      W1l, W1r, Whi1, Wlo1, W2l, W2r, Whi2, Wlo2, W3l, W3r, Whi3, Wlo3, deg,
      stats, Ybf + (size_t)n * 64, n, nbd);

  const int gTile = (n + 63) / 64;
  const int gGath = 2048;

  // ---- merged XCD-local fill + layer-1 GEMM (independent; co-scheduled)
  const int bps = 128;
  const int F = 8 * bps;  // fill blocks, shard = bid & 7
  const int G = gTile;
  fill_gemm1<<<F + G, 256, 0, stream>>>(ei, deg, ell, E, n, bps, x, b1, Whi1,
                                        Wlo1, Ybf, Yrbf, F, G);
  gather_combine<<<gGath, 256, 0, stream>>>(Ybf, Yrbf, ell, deg, Tbf,
                                            stats + 0, n);

  // ---- layer 2 (BN1 finalize + norm fused into GEMM A-loads; bias b2)
  gemm_mfma<64, true, true><<<gTile, 256, 0, stream>>>(
      Tbf, stats + 0, g1, be1, b2, Whi2, Wlo2, Ybf, Yrbf, n);
  gather_combine<<<gGath, 256, 0, stream>>>(Ybf, Yrbf, ell, deg, Tbf,
                                            stats + 1024, n);

  // ---- layer 3 (bias b3)
  gemm_mfma<64, true, true><<<gTile, 256, 0, stream>>>(
      Tbf, stats + 1024, g2, be2, b3, Whi3, Wlo3, Ybf, Yrbf, n);
  gather_combine<<<gGath, 256, 0, stream>>>(Ybf, Yrbf, ell, deg, Tbf,
                                            stats + 2048, n);

  // ---- fusion MLP (BN3 finalize + norm fused in)
  fusion_fused<<<gTile, 256, 0, stream>>>(Tbf, stats + 2048, g3, be3, xgb, Wf1,
                                          bf1, Wf2, bf2, out, n);
}